// Round 12
// baseline (123.467 us; speedup 1.0000x reference)
//
#include <hip/hip_runtime.h>
#include <stdint.h>

// BConv2d via MFMA i8 implicit GEMM (R10-verified core + software pipeline).
// out = conv2d(sign(x), sign(w), pad=1) + b ; N=32, Cin=256, H=W=56, Cout=256, K=3.
//
// sign as i8 {+1,-1}, zero padding as i8 0 (exact, no border correction).
// conv = 9 tap-shifted GEMMs, K=256, i32 acc via v_mfma_i32_32x32x32_i8.
// C/D layout: col=lane&31, row=(reg&3)+8*(reg>>2)+4*(lane>>5) (verified R8-R10).
//
// R11 lesson: fp4 mfma_scale is NOT A/B-layout-symmetric (absmax 268) -> i8.
// R10 lesson: latency-bound, MfmaUtil 34% -- per k-group 3 L2 A-loads
// (~200cy) + 4 LDS reads then only 48cy MFMA; 4 waves/SIMD don't cover it.
// R12: (1) explicit 1-deep software pipeline over the 24 (dw,c8) groups --
// prefetch next group's A+B into named regs during current MFMAs (all
// indices static under full unroll; ~110 VGPR < 128 cap, no spill);
// (2) wq re-laid out so each wave's 72 A-fragments are CONTIGUOUS 1KB blocks
// in exact loop order (L2 row locality) instead of 8KB/192KB strides.

#define NBATCH 32
#define CIN    256
#define COUT   256
#define HH     56
#define WW     56
#define HW     (HH*WW)          // 3136
#define NPIX   (NBATCH*HW)      // 100352

#define PW    58                // padded bit-image width/height
#define PROW  (PW*8)            // 464 words per padded row
#define PIMG  (PW*PW*8)         // 26912 words per padded image

#define XP_BYTES  ((size_t)NBATCH * PIMG * 4)  // 3,444,736 (16-aligned)
#define WQ_BYTES  ((size_t)8 * 72 * 1024)      // 589,824

typedef int i32x4  __attribute__((ext_vector_type(4)));
typedef int i32x16 __attribute__((ext_vector_type(16)));

// ---- pack x bits: wave handles 64 channels (2 words) for 64 pixels
__global__ __launch_bounds__(256) void pack_x_kernel(
    const float* __restrict__ x, uint32_t* __restrict__ xp)
{
    int lane = threadIdx.x & 63;
    int wv   = threadIdx.x >> 6;               // 0..3 -> channel group
    int pix  = blockIdx.x * 64 + lane;         // 1568 blocks * 64 == NPIX
    int n  = pix / HW;
    int hw = pix - n * HW;
    int h  = hw / WW;
    int w_ = hw - h * WW;
    const float* xb = x + ((size_t)n * CIN + (size_t)wv * 64) * HW + hw;

    uint32_t w0 = 0, w1 = 0;
    #pragma unroll
    for (int j = 0; j < 32; ++j) {
        w0 |= (xb[(size_t)j * HW]        >= 0.0f ? 1u : 0u) << j;
        w1 |= (xb[(size_t)(j + 32) * HW] >= 0.0f ? 1u : 0u) << j;
    }
    uint32_t* dst = xp + (size_t)n * PIMG + (size_t)(h + 1) * PROW
                       + (size_t)(w_ + 1) * 8 + wv * 2;
    *(uint2*)dst = make_uint2(w0, w1);
}

// ---- pack w -> i8 {+1,-1}, per-wave-contiguous stream layout:
// wq3[cog][ (dw*8+c8)*3+dh ][co&31][32B-k-slice], fragment = 1KB, 72/cog.
// Byte s of the co-row covers ci = 32*c8 + s (same values as R10's layout).
__global__ __launch_bounds__(256) void pack_w3_kernel(
    const float* __restrict__ w, int8_t* __restrict__ wq3)
{
    int co = blockIdx.x, ci = threadIdx.x;
    const float* wb = w + ((size_t)co * CIN + ci) * 9;
    int cog = co >> 5, l = co & 31, c8 = ci >> 5, s = ci & 31;
    int8_t* base = wq3 + (size_t)cog * 73728 + (size_t)l * 32 + s;
    #pragma unroll
    for (int dh = 0; dh < 3; ++dh) {
        #pragma unroll
        for (int dw = 0; dw < 3; ++dw) {
            int t = dh * 3 + dw;
            base[(size_t)((dw * 8 + c8) * 3 + dh) * 1024] =
                (wb[t] >= 0.0f) ? (int8_t)1 : (int8_t)-1;
        }
    }
}

// ---- conv
#define LOADG(gi, A0, A1, A2, B0, B1, B2, B3) { \
    const int dw_ = (gi) >> 3, c8_ = (gi) & 7; \
    const int col_ = l31 + cb * 32 + dw_; \
    const int sw_ = (col_ & 15) << 4; \
    const char* xc_ = xtb + (col_ << 8); \
    const int sx_ = ((c8_ << 5) + hi16) ^ sw_; \
    B0 = *(const i32x4*)(xc_ + ((0 * 66) << 8) + sx_); \
    B1 = *(const i32x4*)(xc_ + ((1 * 66) << 8) + sx_); \
    B2 = *(const i32x4*)(xc_ + ((2 * 66) << 8) + sx_); \
    B3 = *(const i32x4*)(xc_ + ((3 * 66) << 8) + sx_); \
    const char* wa_ = wqc + (size_t)((dw_ * 8 + c8_) * 3) * 1024; \
    A0 = *(const i32x4*)(wa_); \
    A1 = *(const i32x4*)(wa_ + 1024); \
    A2 = *(const i32x4*)(wa_ + 2048); }

__global__ __launch_bounds__(512, 4) void bconv_kernel(
    const uint32_t* __restrict__ xp, const int8_t* __restrict__ wq3,
    const float* __restrict__ bias, float* __restrict__ out)
{
    __shared__ __align__(16) int8_t xt[4][66][256];   // 67,584 B
    __shared__ float bsh[256];

    int bx = blockIdx.x;               // 0..895
    int n  = bx / 28;
    int hb = bx - n * 28;
    int h  = hb * 2;                   // output rows h, h+1
    int tid = threadIdx.x, lane = tid & 63, wv = tid >> 6;

    if (tid < 256) bsh[tid] = bias[tid];

    // expand packed sign bits -> i8 (+1/-1); borders & cols>=58 -> 0
    const uint32_t* xpb = xp + (size_t)n * PIMG;
    for (int e = tid; e < 4 * 66 * 64; e += 512) {   // 33 iters exactly
        int pr  = e / (66 * 64);
        int rem = e - pr * (66 * 64);
        int col = rem >> 6;
        int d   = rem & 63;            // output dword = 4 ci
        int prg = h + pr;              // padded global row
        bool val = (prg >= 1) & (prg <= 56) & (col >= 1) & (col <= 56);
        uint32_t wvv = 0;
        if (val) wvv = xpb[(size_t)prg * PROW + col * 8 + (d >> 3)];
        uint32_t nib = (wvv >> ((d & 7) * 4)) & 0xFu;
        uint32_t sp  = (nib * 0x00204081u) & 0x01010101u;   // bit k -> byte k
        uint32_t o   = val ? __builtin_amdgcn_perm(0u, 0x000001FFu, sp) : 0u;
        uint32_t ba  = (uint32_t)((((pr * 66 + col) << 8) | (d << 2))
                                  ^ ((col & 15) << 4));
        *(uint32_t*)((char*)&xt[0][0][0] + ba) = o;
    }
    __syncthreads();

    int l31  = lane & 31;
    int hi16 = (lane >> 5) << 4;
    const char* wqc = (const char*)wq3 + (size_t)wv * 73728
                    + (size_t)l31 * 32 + hi16;
    const char* xtb = (const char*)&xt[0][0][0];

    for (int cb = 0; cb < 2; ++cb) {
        i32x16 accA = {0}, accB = {0};     // output rows h, h+1
        i32x4 a0, a1, a2, b0, b1, b2, b3;
        i32x4 na0, na1, na2, nb0, nb1, nb2, nb3;

        LOADG(0, a0, a1, a2, b0, b1, b2, b3)
        #pragma unroll
        for (int gi = 0; gi < 24; ++gi) {
            if (gi < 23) { LOADG(gi + 1, na0, na1, na2, nb0, nb1, nb2, nb3) }
            accA = __builtin_amdgcn_mfma_i32_32x32x32_i8(a0, b0, accA, 0, 0, 0);
            accB = __builtin_amdgcn_mfma_i32_32x32x32_i8(a0, b1, accB, 0, 0, 0);
            accA = __builtin_amdgcn_mfma_i32_32x32x32_i8(a1, b1, accA, 0, 0, 0);
            accB = __builtin_amdgcn_mfma_i32_32x32x32_i8(a1, b2, accB, 0, 0, 0);
            accA = __builtin_amdgcn_mfma_i32_32x32x32_i8(a2, b2, accA, 0, 0, 0);
            accB = __builtin_amdgcn_mfma_i32_32x32x32_i8(a2, b3, accB, 0, 0, 0);
            if (gi < 23) {
                a0 = na0; a1 = na1; a2 = na2;
                b0 = nb0; b1 = nb1; b2 = nb2; b3 = nb3;
            }
        }

        // epilogue: C col=pixel(lane&31 within colblk), row=(r&3)+8*(r>>2)+4*(lane>>5)
        int pix = cb * 32 + l31;
        if (pix < WW) {
            float* op = out + (size_t)n * COUT * HW + (size_t)h * WW + pix;
            #pragma unroll
            for (int r = 0; r < 16; ++r) {
                int row = (r & 3) + 8 * (r >> 2) + ((lane >> 5) << 2);
                int co  = (wv << 5) + row;
                float bb = bsh[co];
                op[(size_t)co * HW]      = (float)accA[r] + bb;
                op[(size_t)co * HW + WW] = (float)accB[r] + bb;
            }
        }
    }
}

extern "C" void kernel_launch(void* const* d_in, const int* in_sizes, int n_in,
                              void* d_out, int out_size, void* d_ws, size_t ws_size,
                              hipStream_t stream) {
    const float* x = (const float*)d_in[0];
    const float* w = (const float*)d_in[1];
    const float* b = (const float*)d_in[2];
    float* out = (float*)d_out;

    uint32_t* xp  = (uint32_t*)d_ws;
    int8_t*   wq3 = (int8_t*)((char*)d_ws + XP_BYTES);

    pack_x_kernel<<<NPIX / 64, 256, 0, stream>>>(x, xp);
    pack_w3_kernel<<<COUT, 256, 0, stream>>>(w, wq3);

    bconv_kernel<<<NBATCH * (HH / 2), 512, 0, stream>>>(xp, wq3, b, out);
}